// Round 10
// baseline (192.902 us; speedup 1.0000x reference)
//
#include <hip/hip_runtime.h>
#include <math.h>
#include <stdint.h>

#define NLEV 16
#define TBL 524288
#define TMASK (TBL - 1)
#define BLOCK 256
#define SPT 4            // samples per thread in encode
#define MSPT 2           // samples per thread in MLP
#define P1 2654435761u
#define P2 805459861u

struct ResArr { float r[NLEV]; };

typedef __attribute__((ext_vector_type(4))) float f32x4;
// 8B-aligned 16B load (table entries are float2-aligned; dwordx4 only needs dword align)
struct __attribute__((packed, aligned(8))) f4wrap { f32x4 v; };

__device__ __forceinline__ float silu_f(float v) {
    return __fdividef(v, 1.0f + __expf(-v));
}

// ---------------- Kernel A: hash-grid encode ----------------
// Phase-split level->XCD mapping (each XCD's L2 holds exactly one 4MB slice),
// corner pairing (dim0 hash coeff == 1 -> corners c,c+4 are adjacent entries:
// one dwordx4 covers both), SPT=4 samples/thread for 16 loads in flight.
__global__ void __launch_bounds__(BLOCK)
encode_kernel(const float* __restrict__ x,
              const float* __restrict__ emb,
              float2* __restrict__ enc_ws,
              int nsamp, ResArr res)
{
    const int bid  = blockIdx.x;
    const int half = gridDim.x >> 1;
    int lvl, chunk;
    if (bid < half) { lvl = bid & 7;               chunk = bid >> 3; }
    else            { lvl = 8 + ((bid - half) & 7); chunk = (bid - half) >> 3; }

    const int t  = threadIdx.x;
    const int s0 = chunk * (BLOCK * SPT) + t;
    const float rs = res.r[lvl];
    const float* tabf = emb + (size_t)lvl * TBL * 2;   // float view of level slice

    uint32_t i0[SPT][4];
    float w0[SPT], w1[SPT], w2[SPT];
    uint32_t bad = 0;

    #pragma unroll
    for (int p = 0; p < SPT; ++p) {
        const int s = s0 + p * BLOCK;
        const float xv0 = __builtin_nontemporal_load(&x[(size_t)s * 3 + 0]);
        const float xv1 = __builtin_nontemporal_load(&x[(size_t)s * 3 + 1]);
        const float xv2 = __builtin_nontemporal_load(&x[(size_t)s * 3 + 2]);
        const float g0 = (xv0 + 1.0f) * 0.5f * rs;
        const float g1 = (xv1 + 1.0f) * 0.5f * rs;
        const float g2 = (xv2 + 1.0f) * 0.5f * rs;
        const float f0 = floorf(g0), f1 = floorf(g1), f2 = floorf(g2);
        w0[p] = g0 - f0; w1[p] = g1 - f1; w2[p] = g2 - f2;
        const uint32_t hb = (uint32_t)f0 + (uint32_t)f1 * P1 + (uint32_t)f2 * P2;
        #pragma unroll
        for (int q = 0; q < 4; ++q) {     // q: (dim1,dim2) corner bits; dim0 paired
            uint32_t h = hb;
            if ((q >> 1) & 1) h += P1;
            if (q & 1)        h += P2;
            i0[p][q] = h & TMASK;
            bad |= (uint32_t)(i0[p][q] == TMASK);
        }
    }

    f32x4 v[SPT][4];
    if (__builtin_expect(__any((int)bad), 0)) {
        // rare wrap path: second entry of a pair is index 0
        #pragma unroll
        for (int p = 0; p < SPT; ++p)
            #pragma unroll
            for (int q = 0; q < 4; ++q) {
                const uint32_t a = i0[p][q];
                const uint32_t b = (a + 1u) & TMASK;
                const float2 lo = *(const float2*)(tabf + 2 * (size_t)a);
                const float2 hi = *(const float2*)(tabf + 2 * (size_t)b);
                v[p][q] = f32x4{lo.x, lo.y, hi.x, hi.y};
            }
    } else {
        // fast path: all 16 pair-loads independent & in flight together
        #pragma unroll
        for (int p = 0; p < SPT; ++p)
            #pragma unroll
            for (int q = 0; q < 4; ++q)
                v[p][q] = ((const f4wrap*)(tabf + 2 * (size_t)i0[p][q]))->v;
    }

    #pragma unroll
    for (int p = 0; p < SPT; ++p) {
        const float om0 = 1.0f - w0[p], om1 = 1.0f - w1[p], om2 = 1.0f - w2[p];
        float e0 = 0.0f, e1 = 0.0f;
        #pragma unroll
        for (int q = 0; q < 4; ++q) {
            float wb = (((q >> 1) & 1) ? w1[p] : om1) * ((q & 1) ? w2[p] : om2);
            const float c0 = om0 * wb;          // corner with dim0 bit = 0
            const float c1 = w0[p] * wb;        // corner with dim0 bit = 1
            e0 = fmaf(c0, v[p][q].x, fmaf(c1, v[p][q].z, e0));
            e1 = fmaf(c0, v[p][q].y, fmaf(c1, v[p][q].w, e1));
        }
        const int s = s0 + p * BLOCK;
        union { float2 f; unsigned long long u; } pk;
        pk.f.x = e0; pk.f.y = e1;
        __builtin_nontemporal_store(pk.u,
            (unsigned long long*)&enc_ws[(size_t)lvl * nsamp + s]);
    }
}

// ---------------- Kernel B: MLP 32 -> 64 -> 64 -> 1 ----------------
// DS/VMEM pipe split (round-8 lesson: NEVER mix s_load with ds_read — SMEM
// shares lgkmcnt with DS and returns out-of-order, forcing lgkmcnt(0) drains):
//   - W1 + biases: LDS ds_read_b128 broadcast (512 reads/wave, lgkmcnt).
//   - W2: wave-uniform global_load_dwordx4 (vmcnt, L1-resident 16KB < 32KB).
//     A dummy inline-asm VGPR zero defeats uniformity analysis so the
//     compiler emits vector loads (one broadcast TCP request), not s_load.
__global__ void __launch_bounds__(BLOCK)
mlp_kernel(const float2* __restrict__ enc_ws,
           const float* __restrict__ W1,
           const float* __restrict__ b1,
           const float* __restrict__ W2,
           const float* __restrict__ b2,
           const float* __restrict__ Wout,
           const float* __restrict__ bout,
           float* __restrict__ out, int nsamp)
{
    __shared__ float sW1[64 * 32];
    __shared__ float sB1[64];
    __shared__ float sB2[64];
    __shared__ float sWo[64];
    __shared__ float sBo[1];

    const int t = threadIdx.x;

    // cooperative coalesced staging: W1 (512 float4)
    {
        const float4* w1v = (const float4*)W1;
        float4* s1v = (float4*)sW1;
        #pragma unroll
        for (int i = 0; i < 2; ++i) s1v[t + i * BLOCK] = w1v[t + i * BLOCK];
        if (t < 64) {
            sB1[t] = b1[t];
            sB2[t] = b2[t];
            sWo[t] = Wout[t];
        }
        if (t == 0) sBo[0] = bout[0];
    }
    __syncthreads();

    // per-lane zero the compiler cannot prove uniform -> forces VMEM vector
    // loads for W2 (vmcnt pipe) instead of s_load (lgkmcnt, entangles DS)
    int zero;
    asm volatile("v_mov_b32 %0, 0" : "=v"(zero));

    const int sA = blockIdx.x * (BLOCK * MSPT) + t;
    const int sB = sA + BLOCK;

    float encA[2 * NLEV], encB[2 * NLEV];
    #pragma unroll
    for (int l = 0; l < NLEV; ++l) {
        // nontemporal (8B scalar form): don't evict W2's L1 lines
        union { unsigned long long u; float f[2]; } ua, ub;
        ua.u = __builtin_nontemporal_load(
            (const unsigned long long*)&enc_ws[(size_t)l * nsamp + sA]);
        ub.u = __builtin_nontemporal_load(
            (const unsigned long long*)&enc_ws[(size_t)l * nsamp + sB]);
        encA[2 * l] = ua.f[0]; encA[2 * l + 1] = ua.f[1];
        encB[2 * l] = ub.f[0]; encB[2 * l + 1] = ub.f[1];
    }

    float hA[64], hB[64];
    #pragma unroll
    for (int i = 0; i < 64; ++i) {
        const float bi = sB1[i];
        float a = bi, b = bi;
        #pragma unroll
        for (int k = 0; k < 32; k += 4) {
            const float4 w = *(const float4*)&sW1[i * 32 + k];  // ds_read_b128 broadcast
            a = fmaf(encA[k],     w.x, a); b = fmaf(encB[k],     w.x, b);
            a = fmaf(encA[k + 1], w.y, a); b = fmaf(encB[k + 1], w.y, b);
            a = fmaf(encA[k + 2], w.z, a); b = fmaf(encB[k + 2], w.z, b);
            a = fmaf(encA[k + 3], w.w, a); b = fmaf(encB[k + 3], w.w, b);
        }
        hA[i] = silu_f(a);
        hB[i] = silu_f(b);
    }

    float oA = sBo[0], oB = sBo[0];
    #pragma unroll
    for (int i = 0; i < 64; ++i) {
        const float bi = sB2[i];
        float a = bi, b = bi;
        #pragma unroll
        for (int k = 0; k < 64; k += 4) {
            // uniform-address vector load: one TCP request, broadcast, L1-hit
            const float4 w = *(const float4*)(W2 + i * 64 + k + zero);
            a = fmaf(hA[k],     w.x, a); b = fmaf(hB[k],     w.x, b);
            a = fmaf(hA[k + 1], w.y, a); b = fmaf(hB[k + 1], w.y, b);
            a = fmaf(hA[k + 2], w.z, a); b = fmaf(hB[k + 2], w.z, b);
            a = fmaf(hA[k + 3], w.w, a); b = fmaf(hB[k + 3], w.w, b);
        }
        const float wo = sWo[i];
        oA = fmaf(silu_f(a), wo, oA);
        oB = fmaf(silu_f(b), wo, oB);
    }

    out[sA] = oA;
    out[sB] = oB;
}

// ---------------- Fallback: monolithic (if ws too small) ----------------
__global__ void __launch_bounds__(BLOCK)
hashgrid_mlp_kernel(const float* __restrict__ x,
                    const float* __restrict__ emb,
                    const float* __restrict__ W1,
                    const float* __restrict__ b1,
                    const float* __restrict__ W2,
                    const float* __restrict__ b2,
                    const float* __restrict__ Wout,
                    const float* __restrict__ bout,
                    float* __restrict__ out,
                    ResArr res)
{
    const int t = threadIdx.x;
    const int s = blockIdx.x * BLOCK + t;

    const float xn0 = (x[(size_t)s * 3 + 0] + 1.0f) * 0.5f;
    const float xn1 = (x[(size_t)s * 3 + 1] + 1.0f) * 0.5f;
    const float xn2 = (x[(size_t)s * 3 + 2] + 1.0f) * 0.5f;

    float enc[2 * NLEV];
    #pragma unroll
    for (int l = 0; l < NLEV; ++l) {
        const float rs = res.r[l];
        const float g0 = xn0 * rs, g1 = xn1 * rs, g2 = xn2 * rs;
        const float f0 = floorf(g0), f1 = floorf(g1), f2 = floorf(g2);
        const float w0 = g0 - f0, w1 = g1 - f1, w2 = g2 - f2;
        const uint32_t hb = (uint32_t)f0 + (uint32_t)f1 * P1 + (uint32_t)f2 * P2;
        const float2* tab = (const float2*)emb + (size_t)l * TBL;
        const float om0 = 1.0f - w0, om1 = 1.0f - w1, om2 = 1.0f - w2;
        float e0 = 0.0f, e1 = 0.0f;
        #pragma unroll
        for (int c = 0; c < 8; ++c) {
            const uint32_t cb0 = (c >> 2) & 1, cb1 = (c >> 1) & 1, cb2 = c & 1;
            uint32_t h = hb;
            if (cb0) h += 1u;
            if (cb1) h += P1;
            if (cb2) h += P2;
            h &= TMASK;
            const float2 vv = tab[h];
            float wt = (cb0 ? w0 : om0) * (cb1 ? w1 : om1);
            wt *= (cb2 ? w2 : om2);
            e0 = fmaf(wt, vv.x, e0);
            e1 = fmaf(wt, vv.y, e1);
        }
        enc[2 * l + 0] = e0;
        enc[2 * l + 1] = e1;
    }

    float h1[64];
    #pragma unroll
    for (int i = 0; i < 64; ++i) {
        float acc = b1[i];
        #pragma unroll
        for (int k = 0; k < 32; ++k)
            acc = fmaf(enc[k], W1[i * 32 + k], acc);
        h1[i] = silu_f(acc);
    }
    float o = bout[0];
    #pragma unroll
    for (int i = 0; i < 64; ++i) {
        float acc = b2[i];
        #pragma unroll
        for (int k = 0; k < 64; ++k)
            acc = fmaf(h1[k], W2[i * 64 + k], acc);
        o = fmaf(silu_f(acc), Wout[i], o);
    }
    out[s] = o;
}

extern "C" void kernel_launch(void* const* d_in, const int* in_sizes, int n_in,
                              void* d_out, int out_size, void* d_ws, size_t ws_size,
                              hipStream_t stream) {
    const float* x    = (const float*)d_in[0];
    const float* emb  = (const float*)d_in[1];
    const float* W1   = (const float*)d_in[2];
    const float* b1   = (const float*)d_in[3];
    const float* W2   = (const float*)d_in[4];
    const float* b2   = (const float*)d_in[5];
    const float* Wout = (const float*)d_in[6];
    const float* bout = (const float*)d_in[7];
    float* out = (float*)d_out;

    ResArr res;
    const double lg0 = log(16.0), lg1 = log(2048.0);
    for (int i = 0; i < NLEV; ++i)
        res.r[i] = (float)exp(lg0 + (lg1 - lg0) * (double)i / 15.0);

    const int n = in_sizes[0] / 3;                     // 262144 samples
    const size_t ws_needed = (size_t)n * NLEV * sizeof(float2);

    if (ws_size >= ws_needed) {
        float2* enc_ws = (float2*)d_ws;
        const int chunks = n / (BLOCK * SPT);          // 256
        dim3 gridA(2 * 8 * chunks);                    // 4096 blocks, phase-split
        encode_kernel<<<gridA, BLOCK, 0, stream>>>(x, emb, enc_ws, n, res);
        dim3 gridB(n / (BLOCK * MSPT));                // 512 blocks
        mlp_kernel<<<gridB, BLOCK, 0, stream>>>(enc_ws, W1, b1, W2, b2,
                                                Wout, bout, out, n);
    } else {
        dim3 grid(n / BLOCK);
        hashgrid_mlp_kernel<<<grid, BLOCK, 0, stream>>>(x, emb, W1, b1, W2, b2,
                                                        Wout, bout, out, res);
    }
}

// Round 11
// 175.093 us; speedup vs baseline: 1.1017x; 1.1017x over previous
//
#include <hip/hip_runtime.h>
#include <math.h>
#include <stdint.h>

#define NLEV 16
#define TBL 524288
#define TMASK (TBL - 1)
#define BLOCK 256
#define SPT 4            // samples per thread in encode
#define MSPT 2           // samples per thread in MLP
#define P1 2654435761u
#define P2 805459861u

struct ResArr { float r[NLEV]; };

typedef __attribute__((ext_vector_type(4))) float f32x4;
// 8B-aligned 16B load (table entries are float2-aligned; dwordx4 only needs dword align)
struct __attribute__((packed, aligned(8))) f4wrap { f32x4 v; };

__device__ __forceinline__ float silu_f(float v) {
    return __fdividef(v, 1.0f + __expf(-v));
}

// ---------------- Kernel A: hash-grid encode ----------------
// Phase-split level->XCD mapping (each XCD's L2 holds exactly one 4MB slice),
// corner pairing (dim0 hash coeff == 1 -> corners c,c+4 are adjacent entries:
// one dwordx4 covers both), SPT=4 samples/thread for 16 loads in flight.
// Pinned at ~105us by L2 scattered-request throughput (~8 req/cyc/XCD).
__global__ void __launch_bounds__(BLOCK)
encode_kernel(const float* __restrict__ x,
              const float* __restrict__ emb,
              float2* __restrict__ enc_ws,
              int nsamp, ResArr res)
{
    const int bid  = blockIdx.x;
    const int half = gridDim.x >> 1;
    int lvl, chunk;
    if (bid < half) { lvl = bid & 7;               chunk = bid >> 3; }
    else            { lvl = 8 + ((bid - half) & 7); chunk = (bid - half) >> 3; }

    const int t  = threadIdx.x;
    const int s0 = chunk * (BLOCK * SPT) + t;
    const float rs = res.r[lvl];
    const float* tabf = emb + (size_t)lvl * TBL * 2;   // float view of level slice

    uint32_t i0[SPT][4];
    float w0[SPT], w1[SPT], w2[SPT];
    uint32_t bad = 0;

    #pragma unroll
    for (int p = 0; p < SPT; ++p) {
        const int s = s0 + p * BLOCK;
        const float xv0 = __builtin_nontemporal_load(&x[(size_t)s * 3 + 0]);
        const float xv1 = __builtin_nontemporal_load(&x[(size_t)s * 3 + 1]);
        const float xv2 = __builtin_nontemporal_load(&x[(size_t)s * 3 + 2]);
        const float g0 = (xv0 + 1.0f) * 0.5f * rs;
        const float g1 = (xv1 + 1.0f) * 0.5f * rs;
        const float g2 = (xv2 + 1.0f) * 0.5f * rs;
        const float f0 = floorf(g0), f1 = floorf(g1), f2 = floorf(g2);
        w0[p] = g0 - f0; w1[p] = g1 - f1; w2[p] = g2 - f2;
        const uint32_t hb = (uint32_t)f0 + (uint32_t)f1 * P1 + (uint32_t)f2 * P2;
        #pragma unroll
        for (int q = 0; q < 4; ++q) {     // q: (dim1,dim2) corner bits; dim0 paired
            uint32_t h = hb;
            if ((q >> 1) & 1) h += P1;
            if (q & 1)        h += P2;
            i0[p][q] = h & TMASK;
            bad |= (uint32_t)(i0[p][q] == TMASK);
        }
    }

    f32x4 v[SPT][4];
    if (__builtin_expect(__any((int)bad), 0)) {
        // rare wrap path: second entry of a pair is index 0
        #pragma unroll
        for (int p = 0; p < SPT; ++p)
            #pragma unroll
            for (int q = 0; q < 4; ++q) {
                const uint32_t a = i0[p][q];
                const uint32_t b = (a + 1u) & TMASK;
                const float2 lo = *(const float2*)(tabf + 2 * (size_t)a);
                const float2 hi = *(const float2*)(tabf + 2 * (size_t)b);
                v[p][q] = f32x4{lo.x, lo.y, hi.x, hi.y};
            }
    } else {
        // fast path: all 16 pair-loads independent & in flight together
        #pragma unroll
        for (int p = 0; p < SPT; ++p)
            #pragma unroll
            for (int q = 0; q < 4; ++q)
                v[p][q] = ((const f4wrap*)(tabf + 2 * (size_t)i0[p][q]))->v;
    }

    #pragma unroll
    for (int p = 0; p < SPT; ++p) {
        const float om0 = 1.0f - w0[p], om1 = 1.0f - w1[p], om2 = 1.0f - w2[p];
        float e0 = 0.0f, e1 = 0.0f;
        #pragma unroll
        for (int q = 0; q < 4; ++q) {
            float wb = (((q >> 1) & 1) ? w1[p] : om1) * ((q & 1) ? w2[p] : om2);
            const float c0 = om0 * wb;          // corner with dim0 bit = 0
            const float c1 = w0[p] * wb;        // corner with dim0 bit = 1
            e0 = fmaf(c0, v[p][q].x, fmaf(c1, v[p][q].z, e0));
            e1 = fmaf(c0, v[p][q].y, fmaf(c1, v[p][q].w, e1));
        }
        const int s = s0 + p * BLOCK;
        union { float2 f; unsigned long long u; } pk;
        pk.f.x = e0; pk.f.y = e1;
        __builtin_nontemporal_store(pk.u,
            (unsigned long long*)&enc_ws[(size_t)lvl * nsamp + s]);
    }
}

// ---------------- Kernel B: MLP 32 -> 64 -> 64 -> 1 ----------------
// Pipe phase-separation (lessons: r8 = never interleave s_load with ds_read,
// shared out-of-order lgkmcnt forces drains; r10 = uniform VMEM loads are
// latency-poison at low occupancy):
//   PHASE 1 (layer 1): W1+b1 from LDS only (512 ds_read_b128/wave).
//   PHASE 2 (layer 2+3): W2/b2/Wout/bout via compile-time-uniform indices
//     -> s_load_dwordx16 from K$; 16.5KB footprint is K$-resident (vs r5's
//     thrashing 25KB). No ds_read in this region.
//   sched_barrier(0) between phases stops cross-region s_load hoisting.
__global__ void __launch_bounds__(BLOCK)
mlp_kernel(const float2* __restrict__ enc_ws,
           const float* __restrict__ W1,
           const float* __restrict__ b1,
           const float* __restrict__ W2,
           const float* __restrict__ b2,
           const float* __restrict__ Wout,
           const float* __restrict__ bout,
           float* __restrict__ out, int nsamp)
{
    __shared__ float sW1[64 * 32];
    __shared__ float sB1[64];

    const int t = threadIdx.x;

    // cooperative coalesced staging: W1 (512 float4) + b1
    {
        const float4* w1v = (const float4*)W1;
        float4* s1v = (float4*)sW1;
        #pragma unroll
        for (int i = 0; i < 2; ++i) s1v[t + i * BLOCK] = w1v[t + i * BLOCK];
        if (t < 64) sB1[t] = b1[t];
    }
    __syncthreads();

    const int sA = blockIdx.x * (BLOCK * MSPT) + t;
    const int sB = sA + BLOCK;

    float encA[2 * NLEV], encB[2 * NLEV];
    #pragma unroll
    for (int l = 0; l < NLEV; ++l) {
        union { unsigned long long u; float f[2]; } ua, ub;
        ua.u = *(const unsigned long long*)&enc_ws[(size_t)l * nsamp + sA];
        ub.u = *(const unsigned long long*)&enc_ws[(size_t)l * nsamp + sB];
        encA[2 * l] = ua.f[0]; encA[2 * l + 1] = ua.f[1];
        encB[2 * l] = ub.f[0]; encB[2 * l + 1] = ub.f[1];
    }

    // ---- PHASE 1: layer 1 from LDS ----
    float hA[64], hB[64];
    #pragma unroll
    for (int i = 0; i < 64; ++i) {
        const float bi = sB1[i];
        float a = bi, b = bi;
        #pragma unroll
        for (int k = 0; k < 32; k += 4) {
            const float4 w = *(const float4*)&sW1[i * 32 + k];  // ds_read_b128 broadcast
            a = fmaf(encA[k],     w.x, a); b = fmaf(encB[k],     w.x, b);
            a = fmaf(encA[k + 1], w.y, a); b = fmaf(encB[k + 1], w.y, b);
            a = fmaf(encA[k + 2], w.z, a); b = fmaf(encB[k + 2], w.z, b);
            a = fmaf(encA[k + 3], w.w, a); b = fmaf(encB[k + 3], w.w, b);
        }
        hA[i] = silu_f(a);
        hB[i] = silu_f(b);
    }

    // fence: keep phase-2 s_loads out of the ds_read region (shared lgkmcnt)
    __builtin_amdgcn_sched_barrier(0);

    // ---- PHASE 2: layers 2+3 from scalar K$ (s_load only, no DS) ----
    float oA = bout[0], oB = bout[0];
    #pragma unroll
    for (int i = 0; i < 64; ++i) {
        const float bi = b2[i];
        float a = bi, b = bi;
        #pragma unroll
        for (int k = 0; k < 64; ++k) {
            const float w = W2[i * 64 + k];   // uniform -> s_load_dwordx16 batches
            a = fmaf(hA[k], w, a);
            b = fmaf(hB[k], w, b);
        }
        const float wo = Wout[i];
        oA = fmaf(silu_f(a), wo, oA);
        oB = fmaf(silu_f(b), wo, oB);
    }

    out[sA] = oA;
    out[sB] = oB;
}

// ---------------- Fallback: monolithic (if ws too small) ----------------
__global__ void __launch_bounds__(BLOCK)
hashgrid_mlp_kernel(const float* __restrict__ x,
                    const float* __restrict__ emb,
                    const float* __restrict__ W1,
                    const float* __restrict__ b1,
                    const float* __restrict__ W2,
                    const float* __restrict__ b2,
                    const float* __restrict__ Wout,
                    const float* __restrict__ bout,
                    float* __restrict__ out,
                    ResArr res)
{
    const int t = threadIdx.x;
    const int s = blockIdx.x * BLOCK + t;

    const float xn0 = (x[(size_t)s * 3 + 0] + 1.0f) * 0.5f;
    const float xn1 = (x[(size_t)s * 3 + 1] + 1.0f) * 0.5f;
    const float xn2 = (x[(size_t)s * 3 + 2] + 1.0f) * 0.5f;

    float enc[2 * NLEV];
    #pragma unroll
    for (int l = 0; l < NLEV; ++l) {
        const float rs = res.r[l];
        const float g0 = xn0 * rs, g1 = xn1 * rs, g2 = xn2 * rs;
        const float f0 = floorf(g0), f1 = floorf(g1), f2 = floorf(g2);
        const float w0 = g0 - f0, w1 = g1 - f1, w2 = g2 - f2;
        const uint32_t hb = (uint32_t)f0 + (uint32_t)f1 * P1 + (uint32_t)f2 * P2;
        const float2* tab = (const float2*)emb + (size_t)l * TBL;
        const float om0 = 1.0f - w0, om1 = 1.0f - w1, om2 = 1.0f - w2;
        float e0 = 0.0f, e1 = 0.0f;
        #pragma unroll
        for (int c = 0; c < 8; ++c) {
            const uint32_t cb0 = (c >> 2) & 1, cb1 = (c >> 1) & 1, cb2 = c & 1;
            uint32_t h = hb;
            if (cb0) h += 1u;
            if (cb1) h += P1;
            if (cb2) h += P2;
            h &= TMASK;
            const float2 vv = tab[h];
            float wt = (cb0 ? w0 : om0) * (cb1 ? w1 : om1);
            wt *= (cb2 ? w2 : om2);
            e0 = fmaf(wt, vv.x, e0);
            e1 = fmaf(wt, vv.y, e1);
        }
        enc[2 * l + 0] = e0;
        enc[2 * l + 1] = e1;
    }

    float h1[64];
    #pragma unroll
    for (int i = 0; i < 64; ++i) {
        float acc = b1[i];
        #pragma unroll
        for (int k = 0; k < 32; ++k)
            acc = fmaf(enc[k], W1[i * 32 + k], acc);
        h1[i] = silu_f(acc);
    }
    float o = bout[0];
    #pragma unroll
    for (int i = 0; i < 64; ++i) {
        float acc = b2[i];
        #pragma unroll
        for (int k = 0; k < 64; ++k)
            acc = fmaf(h1[k], W2[i * 64 + k], acc);
        o = fmaf(silu_f(acc), Wout[i], o);
    }
    out[s] = o;
}

extern "C" void kernel_launch(void* const* d_in, const int* in_sizes, int n_in,
                              void* d_out, int out_size, void* d_ws, size_t ws_size,
                              hipStream_t stream) {
    const float* x    = (const float*)d_in[0];
    const float* emb  = (const float*)d_in[1];
    const float* W1   = (const float*)d_in[2];
    const float* b1   = (const float*)d_in[3];
    const float* W2   = (const float*)d_in[4];
    const float* b2   = (const float*)d_in[5];
    const float* Wout = (const float*)d_in[6];
    const float* bout = (const float*)d_in[7];
    float* out = (float*)d_out;

    ResArr res;
    const double lg0 = log(16.0), lg1 = log(2048.0);
    for (int i = 0; i < NLEV; ++i)
        res.r[i] = (float)exp(lg0 + (lg1 - lg0) * (double)i / 15.0);

    const int n = in_sizes[0] / 3;                     // 262144 samples
    const size_t ws_needed = (size_t)n * NLEV * sizeof(float2);

    if (ws_size >= ws_needed) {
        float2* enc_ws = (float2*)d_ws;
        const int chunks = n / (BLOCK * SPT);          // 256
        dim3 gridA(2 * 8 * chunks);                    // 4096 blocks, phase-split
        encode_kernel<<<gridA, BLOCK, 0, stream>>>(x, emb, enc_ws, n, res);
        dim3 gridB(n / (BLOCK * MSPT));                // 512 blocks
        mlp_kernel<<<gridB, BLOCK, 0, stream>>>(enc_ws, W1, b1, W2, b2,
                                                Wout, bout, out, n);
    } else {
        dim3 grid(n / BLOCK);
        hashgrid_mlp_kernel<<<grid, BLOCK, 0, stream>>>(x, emb, W1, b1, W2, b2,
                                                        Wout, bout, out, res);
    }
}

// Round 12
// 166.169 us; speedup vs baseline: 1.1609x; 1.0537x over previous
//
#include <hip/hip_runtime.h>
#include <math.h>
#include <stdint.h>

#define NLEV 16
#define TBL 524288
#define TMASK (TBL - 1)
#define BLOCK 256
#define SPT 4            // samples per thread in encode
#define MSPT 2           // samples per thread in MLP
#define P1 2654435761u
#define P2 805459861u

struct ResArr { float r[NLEV]; };

typedef __attribute__((ext_vector_type(4))) float f32x4;
// 8B-aligned 16B load (table entries are float2-aligned; dwordx4 only needs dword align)
struct __attribute__((packed, aligned(8))) f4wrap { f32x4 v; };

__device__ __forceinline__ float silu_f(float v) {
    return __fdividef(v, 1.0f + __expf(-v));
}

// wave-broadcast read of lane `l` of x (l compile-time-constant or uniform)
__device__ __forceinline__ float RL(float x, int l) {
    return __int_as_float(__builtin_amdgcn_readlane(__float_as_int(x), l));
}

// ---------------- Kernel A: hash-grid encode ----------------
// Phase-split level->XCD mapping (each XCD's L2 holds exactly one 4MB slice),
// corner pairing (dim0 hash coeff == 1 -> corners c,c+4 are adjacent entries:
// one dwordx4 covers both), SPT=4 samples/thread for 16 loads in flight.
// Pinned at ~105us: ~16.8M scattered pair-requests at ~200cy L2-hit latency
// against a per-CU outstanding-request (MSHR) cap — r5 (SPT2,68%occ) == r6
// (SPT4,34%occ) shows occupancy x per-thread-MLP is saturated.
__global__ void __launch_bounds__(BLOCK)
encode_kernel(const float* __restrict__ x,
              const float* __restrict__ emb,
              float2* __restrict__ enc_ws,
              int nsamp, ResArr res)
{
    const int bid  = blockIdx.x;
    const int half = gridDim.x >> 1;
    int lvl, chunk;
    if (bid < half) { lvl = bid & 7;               chunk = bid >> 3; }
    else            { lvl = 8 + ((bid - half) & 7); chunk = (bid - half) >> 3; }

    const int t  = threadIdx.x;
    const int s0 = chunk * (BLOCK * SPT) + t;
    const float rs = res.r[lvl];
    const float* tabf = emb + (size_t)lvl * TBL * 2;   // float view of level slice

    uint32_t i0[SPT][4];
    float w0[SPT], w1[SPT], w2[SPT];
    uint32_t bad = 0;

    #pragma unroll
    for (int p = 0; p < SPT; ++p) {
        const int s = s0 + p * BLOCK;
        const float xv0 = __builtin_nontemporal_load(&x[(size_t)s * 3 + 0]);
        const float xv1 = __builtin_nontemporal_load(&x[(size_t)s * 3 + 1]);
        const float xv2 = __builtin_nontemporal_load(&x[(size_t)s * 3 + 2]);
        const float g0 = (xv0 + 1.0f) * 0.5f * rs;
        const float g1 = (xv1 + 1.0f) * 0.5f * rs;
        const float g2 = (xv2 + 1.0f) * 0.5f * rs;
        const float f0 = floorf(g0), f1 = floorf(g1), f2 = floorf(g2);
        w0[p] = g0 - f0; w1[p] = g1 - f1; w2[p] = g2 - f2;
        const uint32_t hb = (uint32_t)f0 + (uint32_t)f1 * P1 + (uint32_t)f2 * P2;
        #pragma unroll
        for (int q = 0; q < 4; ++q) {     // q: (dim1,dim2) corner bits; dim0 paired
            uint32_t h = hb;
            if ((q >> 1) & 1) h += P1;
            if (q & 1)        h += P2;
            i0[p][q] = h & TMASK;
            bad |= (uint32_t)(i0[p][q] == TMASK);
        }
    }

    f32x4 v[SPT][4];
    if (__builtin_expect(__any((int)bad), 0)) {
        // rare wrap path: second entry of a pair is index 0
        #pragma unroll
        for (int p = 0; p < SPT; ++p)
            #pragma unroll
            for (int q = 0; q < 4; ++q) {
                const uint32_t a = i0[p][q];
                const uint32_t b = (a + 1u) & TMASK;
                const float2 lo = *(const float2*)(tabf + 2 * (size_t)a);
                const float2 hi = *(const float2*)(tabf + 2 * (size_t)b);
                v[p][q] = f32x4{lo.x, lo.y, hi.x, hi.y};
            }
    } else {
        // fast path: all 16 pair-loads independent & in flight together
        #pragma unroll
        for (int p = 0; p < SPT; ++p)
            #pragma unroll
            for (int q = 0; q < 4; ++q)
                v[p][q] = ((const f4wrap*)(tabf + 2 * (size_t)i0[p][q]))->v;
    }

    #pragma unroll
    for (int p = 0; p < SPT; ++p) {
        const float om0 = 1.0f - w0[p], om1 = 1.0f - w1[p], om2 = 1.0f - w2[p];
        float e0 = 0.0f, e1 = 0.0f;
        #pragma unroll
        for (int q = 0; q < 4; ++q) {
            float wb = (((q >> 1) & 1) ? w1[p] : om1) * ((q & 1) ? w2[p] : om2);
            const float c0 = om0 * wb;          // corner with dim0 bit = 0
            const float c1 = w0[p] * wb;        // corner with dim0 bit = 1
            e0 = fmaf(c0, v[p][q].x, fmaf(c1, v[p][q].z, e0));
            e1 = fmaf(c0, v[p][q].y, fmaf(c1, v[p][q].w, e1));
        }
        const int s = s0 + p * BLOCK;
        union { float2 f; unsigned long long u; } pk;
        pk.f.x = e0; pk.f.y = e1;
        __builtin_nontemporal_store(pk.u,
            (unsigned long long*)&enc_ws[(size_t)lvl * nsamp + s]);
    }
}

// ---------------- Kernel B: MLP 32 -> 64 -> 64 -> 1 ----------------
// Distributed-VGPR weights + v_readlane broadcast. Lessons baked in:
//   r7: DS-pipe bound at 1536 ds_read/wave (52us).
//   r8/r11: s_load paths thrash/entangle (shared lgkmcnt, 16KB K$).
//   r10: uniform VMEM loads are latency-poison at low occupancy.
// Here the wave's 64 lanes collectively hold W1 (32 VGPRs) and W2 (64 VGPRs):
//   w1r[r] lane l = W1flat[r*64+l];  W1[i][k] = RL(w1r[(i*32+k)>>6], (i*32+k)&63)
//   w2r[r] lane l = W2[r][l];        W2[i][k] = RL(w2r[i], k)
// One readlane (VALU) feeds two FMAs (MSPT=2). No ds_read/s_load/VMEM in the
// hot loops -> pure VALU. Layer-1 enc is consumed in two k-halves to keep
// peak VGPR ~210 (2 waves/SIMD, no spill).
__global__ void __launch_bounds__(BLOCK, 2)
mlp_kernel(const float2* __restrict__ enc_ws,
           const float* __restrict__ W1,
           const float* __restrict__ b1,
           const float* __restrict__ W2,
           const float* __restrict__ b2,
           const float* __restrict__ Wout,
           const float* __restrict__ bout,
           float* __restrict__ out, int nsamp)
{
    const int t = threadIdx.x;
    const int lane = t & 63;
    const int sA = blockIdx.x * (BLOCK * MSPT) + t;
    const int sB = sA + BLOCK;

    // distributed weight registers (coalesced one-time loads)
    float w1r[32];
    #pragma unroll
    for (int r = 0; r < 32; ++r) w1r[r] = W1[r * 64 + lane];
    const float b1r = b1[lane];
    const float b2r = b2[lane];
    const float wor = Wout[lane];
    const float bo  = bout[0];

    float hA[64], hB[64];
    #pragma unroll
    for (int i = 0; i < 64; ++i) {
        const float bi = RL(b1r, i);
        hA[i] = bi; hB[i] = bi;
    }

    // ---- layer 1, two k-halves (enc half = 16 floats/sample) ----
    #pragma unroll
    for (int h = 0; h < 2; ++h) {
        float eA[16], eB[16];
        #pragma unroll
        for (int l = 0; l < 8; ++l) {
            const int lev = h * 8 + l;
            union { unsigned long long u; float f[2]; } ua, ub;
            ua.u = *(const unsigned long long*)&enc_ws[(size_t)lev * nsamp + sA];
            ub.u = *(const unsigned long long*)&enc_ws[(size_t)lev * nsamp + sB];
            eA[2 * l] = ua.f[0]; eA[2 * l + 1] = ua.f[1];
            eB[2 * l] = ub.f[0]; eB[2 * l + 1] = ub.f[1];
        }
        #pragma unroll
        for (int i = 0; i < 64; ++i) {
            float a = hA[i], b = hB[i];
            #pragma unroll
            for (int k = 0; k < 16; ++k) {
                const int idx = i * 32 + h * 16 + k;     // compile-time constant
                const float w = RL(w1r[idx >> 6], idx & 63);
                a = fmaf(eA[k], w, a);
                b = fmaf(eB[k], w, b);
            }
            hA[i] = a; hB[i] = b;
        }
    }
    #pragma unroll
    for (int i = 0; i < 64; ++i) { hA[i] = silu_f(hA[i]); hB[i] = silu_f(hB[i]); }

    // ---- W2 into 64 regs (after layer 1 so enc regs are free) ----
    float w2r[64];
    #pragma unroll
    for (int r = 0; r < 64; ++r) w2r[r] = W2[r * 64 + lane];

    float oA = bo, oB = bo;
    #pragma unroll
    for (int i = 0; i < 64; ++i) {
        const float bi = RL(b2r, i);
        float a = bi, b = bi;
        #pragma unroll
        for (int k = 0; k < 64; ++k) {
            const float w = RL(w2r[i], k);
            a = fmaf(hA[k], w, a);
            b = fmaf(hB[k], w, b);
        }
        const float wo = RL(wor, i);
        oA = fmaf(silu_f(a), wo, oA);
        oB = fmaf(silu_f(b), wo, oB);
    }

    out[sA] = oA;
    out[sB] = oB;
}

// ---------------- Fallback: monolithic (if ws too small) ----------------
__global__ void __launch_bounds__(BLOCK)
hashgrid_mlp_kernel(const float* __restrict__ x,
                    const float* __restrict__ emb,
                    const float* __restrict__ W1,
                    const float* __restrict__ b1,
                    const float* __restrict__ W2,
                    const float* __restrict__ b2,
                    const float* __restrict__ Wout,
                    const float* __restrict__ bout,
                    float* __restrict__ out,
                    ResArr res)
{
    const int t = threadIdx.x;
    const int s = blockIdx.x * BLOCK + t;

    const float xn0 = (x[(size_t)s * 3 + 0] + 1.0f) * 0.5f;
    const float xn1 = (x[(size_t)s * 3 + 1] + 1.0f) * 0.5f;
    const float xn2 = (x[(size_t)s * 3 + 2] + 1.0f) * 0.5f;

    float enc[2 * NLEV];
    #pragma unroll
    for (int l = 0; l < NLEV; ++l) {
        const float rs = res.r[l];
        const float g0 = xn0 * rs, g1 = xn1 * rs, g2 = xn2 * rs;
        const float f0 = floorf(g0), f1 = floorf(g1), f2 = floorf(g2);
        const float w0 = g0 - f0, w1 = g1 - f1, w2 = g2 - f2;
        const uint32_t hb = (uint32_t)f0 + (uint32_t)f1 * P1 + (uint32_t)f2 * P2;
        const float2* tab = (const float2*)emb + (size_t)l * TBL;
        const float om0 = 1.0f - w0, om1 = 1.0f - w1, om2 = 1.0f - w2;
        float e0 = 0.0f, e1 = 0.0f;
        #pragma unroll
        for (int c = 0; c < 8; ++c) {
            const uint32_t cb0 = (c >> 2) & 1, cb1 = (c >> 1) & 1, cb2 = c & 1;
            uint32_t h = hb;
            if (cb0) h += 1u;
            if (cb1) h += P1;
            if (cb2) h += P2;
            h &= TMASK;
            const float2 vv = tab[h];
            float wt = (cb0 ? w0 : om0) * (cb1 ? w1 : om1);
            wt *= (cb2 ? w2 : om2);
            e0 = fmaf(wt, vv.x, e0);
            e1 = fmaf(wt, vv.y, e1);
        }
        enc[2 * l + 0] = e0;
        enc[2 * l + 1] = e1;
    }

    float h1[64];
    #pragma unroll
    for (int i = 0; i < 64; ++i) {
        float acc = b1[i];
        #pragma unroll
        for (int k = 0; k < 32; ++k)
            acc = fmaf(enc[k], W1[i * 32 + k], acc);
        h1[i] = silu_f(acc);
    }
    float o = bout[0];
    #pragma unroll
    for (int i = 0; i < 64; ++i) {
        float acc = b2[i];
        #pragma unroll
        for (int k = 0; k < 64; ++k)
            acc = fmaf(h1[k], W2[i * 64 + k], acc);
        o = fmaf(silu_f(acc), Wout[i], o);
    }
    out[s] = o;
}

extern "C" void kernel_launch(void* const* d_in, const int* in_sizes, int n_in,
                              void* d_out, int out_size, void* d_ws, size_t ws_size,
                              hipStream_t stream) {
    const float* x    = (const float*)d_in[0];
    const float* emb  = (const float*)d_in[1];
    const float* W1   = (const float*)d_in[2];
    const float* b1   = (const float*)d_in[3];
    const float* W2   = (const float*)d_in[4];
    const float* b2   = (const float*)d_in[5];
    const float* Wout = (const float*)d_in[6];
    const float* bout = (const float*)d_in[7];
    float* out = (float*)d_out;

    ResArr res;
    const double lg0 = log(16.0), lg1 = log(2048.0);
    for (int i = 0; i < NLEV; ++i)
        res.r[i] = (float)exp(lg0 + (lg1 - lg0) * (double)i / 15.0);

    const int n = in_sizes[0] / 3;                     // 262144 samples
    const size_t ws_needed = (size_t)n * NLEV * sizeof(float2);

    if (ws_size >= ws_needed) {
        float2* enc_ws = (float2*)d_ws;
        const int chunks = n / (BLOCK * SPT);          // 256
        dim3 gridA(2 * 8 * chunks);                    // 4096 blocks, phase-split
        encode_kernel<<<gridA, BLOCK, 0, stream>>>(x, emb, enc_ws, n, res);
        dim3 gridB(n / (BLOCK * MSPT));                // 512 blocks
        mlp_kernel<<<gridB, BLOCK, 0, stream>>>(enc_ws, W1, b1, W2, b2,
                                                Wout, bout, out, n);
    } else {
        dim3 grid(n / BLOCK);
        hashgrid_mlp_kernel<<<grid, BLOCK, 0, stream>>>(x, emb, W1, b1, W2, b2,
                                                        Wout, bout, out, res);
    }
}

// Round 13
// 164.247 us; speedup vs baseline: 1.1745x; 1.0117x over previous
//
#include <hip/hip_runtime.h>
#include <math.h>
#include <stdint.h>

#define NLEV 16
#define TBL 524288
#define TMASK (TBL - 1)
#define BLOCK 256
#define SPT 4            // samples per thread in encode
#define MSPT 2           // samples per thread in MLP
#define P1 2654435761u
#define P2 805459861u

struct ResArr { float r[NLEV]; };

typedef __attribute__((ext_vector_type(4))) float f32x4;
// 8B-aligned 16B load (table entries are float2-aligned; dwordx4 only needs dword align)
struct __attribute__((packed, aligned(8))) f4wrap { f32x4 v; };

__device__ __forceinline__ float silu_f(float v) {
    return __fdividef(v, 1.0f + __expf(-v));
}

// wave-broadcast read of lane `l` of x (l compile-time-constant)
__device__ __forceinline__ float RL(float x, int l) {
    return __int_as_float(__builtin_amdgcn_readlane(__float_as_int(x), l));
}

// ---------------- Kernel A: hash-grid encode ----------------
// Phase-split level->XCD mapping (each XCD's L2 holds exactly one 4MB slice),
// corner pairing (dim0 hash coeff == 1 -> corners c,c+4 adjacent: one dwordx4
// covers both), SPT=4. Pinned ~105us: ~65K line-fills/CU through the L1 miss
// path at ~200cy L2-hit latency against the per-CU MSHR cap (r5 SPT2/68%occ
// == r6 SPT4/34%occ confirmed saturation).
__global__ void __launch_bounds__(BLOCK)
encode_kernel(const float* __restrict__ x,
              const float* __restrict__ emb,
              float2* __restrict__ enc_ws,
              int nsamp, ResArr res)
{
    const int bid  = blockIdx.x;
    const int half = gridDim.x >> 1;
    int lvl, chunk;
    if (bid < half) { lvl = bid & 7;               chunk = bid >> 3; }
    else            { lvl = 8 + ((bid - half) & 7); chunk = (bid - half) >> 3; }

    const int t  = threadIdx.x;
    const int s0 = chunk * (BLOCK * SPT) + t;
    const float rs = res.r[lvl];
    const float* tabf = emb + (size_t)lvl * TBL * 2;   // float view of level slice

    uint32_t i0[SPT][4];
    float w0[SPT], w1[SPT], w2[SPT];
    uint32_t bad = 0;

    #pragma unroll
    for (int p = 0; p < SPT; ++p) {
        const int s = s0 + p * BLOCK;
        const float xv0 = __builtin_nontemporal_load(&x[(size_t)s * 3 + 0]);
        const float xv1 = __builtin_nontemporal_load(&x[(size_t)s * 3 + 1]);
        const float xv2 = __builtin_nontemporal_load(&x[(size_t)s * 3 + 2]);
        const float g0 = (xv0 + 1.0f) * 0.5f * rs;
        const float g1 = (xv1 + 1.0f) * 0.5f * rs;
        const float g2 = (xv2 + 1.0f) * 0.5f * rs;
        const float f0 = floorf(g0), f1 = floorf(g1), f2 = floorf(g2);
        w0[p] = g0 - f0; w1[p] = g1 - f1; w2[p] = g2 - f2;
        const uint32_t hb = (uint32_t)f0 + (uint32_t)f1 * P1 + (uint32_t)f2 * P2;
        #pragma unroll
        for (int q = 0; q < 4; ++q) {     // q: (dim1,dim2) corner bits; dim0 paired
            uint32_t h = hb;
            if ((q >> 1) & 1) h += P1;
            if (q & 1)        h += P2;
            i0[p][q] = h & TMASK;
            bad |= (uint32_t)(i0[p][q] == TMASK);
        }
    }

    f32x4 v[SPT][4];
    if (__builtin_expect(__any((int)bad), 0)) {
        // rare wrap path: second entry of a pair is index 0
        #pragma unroll
        for (int p = 0; p < SPT; ++p)
            #pragma unroll
            for (int q = 0; q < 4; ++q) {
                const uint32_t a = i0[p][q];
                const uint32_t b = (a + 1u) & TMASK;
                const float2 lo = *(const float2*)(tabf + 2 * (size_t)a);
                const float2 hi = *(const float2*)(tabf + 2 * (size_t)b);
                v[p][q] = f32x4{lo.x, lo.y, hi.x, hi.y};
            }
    } else {
        // fast path: all 16 pair-loads independent & in flight together
        #pragma unroll
        for (int p = 0; p < SPT; ++p)
            #pragma unroll
            for (int q = 0; q < 4; ++q)
                v[p][q] = ((const f4wrap*)(tabf + 2 * (size_t)i0[p][q]))->v;
    }

    #pragma unroll
    for (int p = 0; p < SPT; ++p) {
        const float om0 = 1.0f - w0[p], om1 = 1.0f - w1[p], om2 = 1.0f - w2[p];
        float e0 = 0.0f, e1 = 0.0f;
        #pragma unroll
        for (int q = 0; q < 4; ++q) {
            float wb = (((q >> 1) & 1) ? w1[p] : om1) * ((q & 1) ? w2[p] : om2);
            const float c0 = om0 * wb;          // corner with dim0 bit = 0
            const float c1 = w0[p] * wb;        // corner with dim0 bit = 1
            e0 = fmaf(c0, v[p][q].x, fmaf(c1, v[p][q].z, e0));
            e1 = fmaf(c0, v[p][q].y, fmaf(c1, v[p][q].w, e1));
        }
        const int s = s0 + p * BLOCK;
        union { float2 f; unsigned long long u; } pk;
        pk.f.x = e0; pk.f.y = e1;
        __builtin_nontemporal_store(pk.u,
            (unsigned long long*)&enc_ws[(size_t)lvl * nsamp + s]);
    }
}

// ---------------- Kernel B: MLP 32 -> 64 -> 64 -> 1 ----------------
// Split weight traffic across the two healthy pipes (scoreboard r7..r12:
// all-LDS 52us DS-bound / all-readlane 59us VALU+I$-heavy / s_load & VMEM
// variants worse):
//   PHASE 1: W1+b1 from LDS (512 ds_read_b128/wave, ~20us DS demand).
//   PHASE 2: W2 distributed across the wave's VGPRs (w2r[r] lane l = W2[r][l]),
//            broadcast via v_readlane (4096 RL, pure VALU; no DS/SMEM/VMEM).
// sched_barrier(0) separates phases: caps VGPR peak (~220, 2 waves/SIMD) and
// keeps one lgkmcnt producer per region.
__global__ void __launch_bounds__(BLOCK, 2)
mlp_kernel(const float2* __restrict__ enc_ws,
           const float* __restrict__ W1,
           const float* __restrict__ b1,
           const float* __restrict__ W2,
           const float* __restrict__ b2,
           const float* __restrict__ Wout,
           const float* __restrict__ bout,
           float* __restrict__ out, int nsamp)
{
    __shared__ float sW1[64 * 32];
    __shared__ float sB1[64];

    const int t = threadIdx.x;
    const int lane = t & 63;

    // cooperative coalesced staging: W1 (512 float4) + b1
    {
        const float4* w1v = (const float4*)W1;
        float4* s1v = (float4*)sW1;
        #pragma unroll
        for (int i = 0; i < 2; ++i) s1v[t + i * BLOCK] = w1v[t + i * BLOCK];
        if (t < 64) sB1[t] = b1[t];
    }
    __syncthreads();

    const int sA = blockIdx.x * (BLOCK * MSPT) + t;
    const int sB = sA + BLOCK;

    float encA[2 * NLEV], encB[2 * NLEV];
    #pragma unroll
    for (int l = 0; l < NLEV; ++l) {
        union { unsigned long long u; float f[2]; } ua, ub;
        ua.u = *(const unsigned long long*)&enc_ws[(size_t)l * nsamp + sA];
        ub.u = *(const unsigned long long*)&enc_ws[(size_t)l * nsamp + sB];
        encA[2 * l] = ua.f[0]; encA[2 * l + 1] = ua.f[1];
        encB[2 * l] = ub.f[0]; encB[2 * l + 1] = ub.f[1];
    }

    // ---- PHASE 1: layer 1 from LDS (identical arithmetic to r7) ----
    float hA[64], hB[64];
    #pragma unroll
    for (int i = 0; i < 64; ++i) {
        const float bi = sB1[i];
        float a = bi, b = bi;
        #pragma unroll
        for (int k = 0; k < 32; k += 4) {
            const float4 w = *(const float4*)&sW1[i * 32 + k];  // ds_read_b128 broadcast
            a = fmaf(encA[k],     w.x, a); b = fmaf(encB[k],     w.x, b);
            a = fmaf(encA[k + 1], w.y, a); b = fmaf(encB[k + 1], w.y, b);
            a = fmaf(encA[k + 2], w.z, a); b = fmaf(encB[k + 2], w.z, b);
            a = fmaf(encA[k + 3], w.w, a); b = fmaf(encB[k + 3], w.w, b);
        }
        hA[i] = silu_f(a);
        hB[i] = silu_f(b);
    }

    // phase fence: enc regs die here; w2r loads stay below (VGPR peak ~220)
    __builtin_amdgcn_sched_barrier(0);

    // ---- PHASE 2: layers 2+3 via distributed-VGPR W2 + readlane ----
    const float b2r = b2[lane];
    const float wor = Wout[lane];
    const float bo  = bout[0];
    float w2r[64];
    #pragma unroll
    for (int r = 0; r < 64; ++r) w2r[r] = W2[r * 64 + lane];

    float oA = bo, oB = bo;
    #pragma unroll
    for (int i = 0; i < 64; ++i) {
        const float bi = RL(b2r, i);
        float a = bi, b = bi;
        #pragma unroll
        for (int k = 0; k < 64; ++k) {
            const float w = RL(w2r[i], k);       // 1 VALU feeds 2 FMAs
            a = fmaf(hA[k], w, a);
            b = fmaf(hB[k], w, b);
        }
        const float wo = RL(wor, i);
        oA = fmaf(silu_f(a), wo, oA);
        oB = fmaf(silu_f(b), wo, oB);
    }

    out[sA] = oA;
    out[sB] = oB;
}

// ---------------- Fallback: monolithic (if ws too small) ----------------
__global__ void __launch_bounds__(BLOCK)
hashgrid_mlp_kernel(const float* __restrict__ x,
                    const float* __restrict__ emb,
                    const float* __restrict__ W1,
                    const float* __restrict__ b1,
                    const float* __restrict__ W2,
                    const float* __restrict__ b2,
                    const float* __restrict__ Wout,
                    const float* __restrict__ bout,
                    float* __restrict__ out,
                    ResArr res)
{
    const int t = threadIdx.x;
    const int s = blockIdx.x * BLOCK + t;

    const float xn0 = (x[(size_t)s * 3 + 0] + 1.0f) * 0.5f;
    const float xn1 = (x[(size_t)s * 3 + 1] + 1.0f) * 0.5f;
    const float xn2 = (x[(size_t)s * 3 + 2] + 1.0f) * 0.5f;

    float enc[2 * NLEV];
    #pragma unroll
    for (int l = 0; l < NLEV; ++l) {
        const float rs = res.r[l];
        const float g0 = xn0 * rs, g1 = xn1 * rs, g2 = xn2 * rs;
        const float f0 = floorf(g0), f1 = floorf(g1), f2 = floorf(g2);
        const float w0 = g0 - f0, w1 = g1 - f1, w2 = g2 - f2;
        const uint32_t hb = (uint32_t)f0 + (uint32_t)f1 * P1 + (uint32_t)f2 * P2;
        const float2* tab = (const float2*)emb + (size_t)l * TBL;
        const float om0 = 1.0f - w0, om1 = 1.0f - w1, om2 = 1.0f - w2;
        float e0 = 0.0f, e1 = 0.0f;
        #pragma unroll
        for (int c = 0; c < 8; ++c) {
            const uint32_t cb0 = (c >> 2) & 1, cb1 = (c >> 1) & 1, cb2 = c & 1;
            uint32_t h = hb;
            if (cb0) h += 1u;
            if (cb1) h += P1;
            if (cb2) h += P2;
            h &= TMASK;
            const float2 vv = tab[h];
            float wt = (cb0 ? w0 : om0) * (cb1 ? w1 : om1);
            wt *= (cb2 ? w2 : om2);
            e0 = fmaf(wt, vv.x, e0);
            e1 = fmaf(wt, vv.y, e1);
        }
        enc[2 * l + 0] = e0;
        enc[2 * l + 1] = e1;
    }

    float h1[64];
    #pragma unroll
    for (int i = 0; i < 64; ++i) {
        float acc = b1[i];
        #pragma unroll
        for (int k = 0; k < 32; ++k)
            acc = fmaf(enc[k], W1[i * 32 + k], acc);
        h1[i] = silu_f(acc);
    }
    float o = bout[0];
    #pragma unroll
    for (int i = 0; i < 64; ++i) {
        float acc = b2[i];
        #pragma unroll
        for (int k = 0; k < 64; ++k)
            acc = fmaf(h1[k], W2[i * 64 + k], acc);
        o = fmaf(silu_f(acc), Wout[i], o);
    }
    out[s] = o;
}

extern "C" void kernel_launch(void* const* d_in, const int* in_sizes, int n_in,
                              void* d_out, int out_size, void* d_ws, size_t ws_size,
                              hipStream_t stream) {
    const float* x    = (const float*)d_in[0];
    const float* emb  = (const float*)d_in[1];
    const float* W1   = (const float*)d_in[2];
    const float* b1   = (const float*)d_in[3];
    const float* W2   = (const float*)d_in[4];
    const float* b2   = (const float*)d_in[5];
    const float* Wout = (const float*)d_in[6];
    const float* bout = (const float*)d_in[7];
    float* out = (float*)d_out;

    ResArr res;
    const double lg0 = log(16.0), lg1 = log(2048.0);
    for (int i = 0; i < NLEV; ++i)
        res.r[i] = (float)exp(lg0 + (lg1 - lg0) * (double)i / 15.0);

    const int n = in_sizes[0] / 3;                     // 262144 samples
    const size_t ws_needed = (size_t)n * NLEV * sizeof(float2);

    if (ws_size >= ws_needed) {
        float2* enc_ws = (float2*)d_ws;
        const int chunks = n / (BLOCK * SPT);          // 256
        dim3 gridA(2 * 8 * chunks);                    // 4096 blocks, phase-split
        encode_kernel<<<gridA, BLOCK, 0, stream>>>(x, emb, enc_ws, n, res);
        dim3 gridB(n / (BLOCK * MSPT));                // 512 blocks
        mlp_kernel<<<gridB, BLOCK, 0, stream>>>(enc_ws, W1, b1, W2, b2,
                                                Wout, bout, out, n);
    } else {
        dim3 grid(n / BLOCK);
        hashgrid_mlp_kernel<<<grid, BLOCK, 0, stream>>>(x, emb, W1, b1, W2, b2,
                                                        Wout, bout, out, res);
    }
}